// Round 3
// baseline (548.913 us; speedup 1.0000x reference)
//
#include <hip/hip_runtime.h>
#include <hip/hip_bf16.h>

typedef _Float16 f16x8 __attribute__((ext_vector_type(8)));
typedef float f32x4 __attribute__((ext_vector_type(4)));
typedef int i32x4 __attribute__((ext_vector_type(4)));

__device__ __forceinline__ float bf2f(unsigned short u) {
  union { unsigned int i; float f; } x; x.i = ((unsigned int)u) << 16; return x.f;
}
// clamp-to-finite fp16 convert: any upstream bug shows as finite wrong value, not NaN
__device__ __forceinline__ _Float16 h16(float f) {
  return (_Float16)fminf(fmaxf(f, -60000.f), 60000.f);
}

__device__ __forceinline__ f16x8 cvt8_bf(const unsigned short* p) {
  union { i32x4 v; unsigned short u[8]; } ld;
  ld.v = *(const i32x4*)p;
  f16x8 r;
#pragma unroll
  for (int j = 0; j < 8; j++) r[j] = h16(bf2f(ld.u[j]));
  return r;
}
__device__ __forceinline__ f16x8 cvt8_f32(const float* p) {
  f32x4 a = *(const f32x4*)p;
  f32x4 b = *(const f32x4*)(p + 4);
  f16x8 r;
#pragma unroll
  for (int j = 0; j < 4; j++) { r[j] = h16(a[j]); r[4 + j] = h16(b[j]); }
  return r;
}

// accurate -log(u): series for u near 1 (1-u is exact by Sterbenz there)
__device__ __forceinline__ float neglog(float u) {
  if (u > 0.99f) {
    const float d = 1.0f - u;
    return d + 0.5f * d * d + (1.0f / 3.0f) * d * d * d;
  }
  return -__logf(u);
}

// butterfly (max, sum) softmax-state reduction across 64 lanes
__device__ __forceinline__ void wred(float& m, float& s) {
#pragma unroll
  for (int off = 1; off < 64; off <<= 1) {
    float mo = __shfl_xor(m, off, 64);
    float so = __shfl_xor(s, off, 64);
    float mn = fmaxf(m, mo);
    s = s * __expf(m - mn) + so * __expf(mo - mn);
    m = mn;
  }
}

// ---------------------------------------------------------------------------
// Kernel 0: input dtype detector. gumbel_u in (1e-6, 1-1e-6).
// bf16 buffer: every even short decodes into (8e-7, 1.0]. fp32 buffer: even
// shorts are random low mantissa halves -> P(all 64 pass) ~ 0.
// flag: 0 = bf16 inputs, 1 = fp32 inputs.
// ---------------------------------------------------------------------------
__global__ void detect_dtype(const unsigned short* __restrict__ g, int* __restrict__ flag) {
  const int lane = threadIdx.x;  // 64 threads, one wave
  const float f = bf2f(g[lane * 2]);
  const bool ok = (f >= 8e-7f) && (f <= 1.0f);
  const unsigned long long m = __ballot(ok);
  if (lane == 0) *flag = (m == ~0ull) ? 0 : 1;
}

// ---------------------------------------------------------------------------
// Kernel 1: QKV projection.  C[n, o] = hidden[n,:] . W[o,:] + bias[o]
// hidden [2048,1024], W [1024,1024] row-major (NT gemm), dtype per flag.
// q,k stored fp16 [B,H,S,64]; v stored transposed fp16 [B,H,64,S].
// ---------------------------------------------------------------------------
__global__ __launch_bounds__(256) void qkv_gemm(
    const unsigned short* __restrict__ hidden,
    const unsigned short* __restrict__ Wq, const unsigned short* __restrict__ bq,
    const unsigned short* __restrict__ Wk, const unsigned short* __restrict__ bk,
    const unsigned short* __restrict__ Wv, const unsigned short* __restrict__ bv,
    const int* __restrict__ flag,
    _Float16* __restrict__ q_ws, _Float16* __restrict__ k_ws,
    _Float16* __restrict__ vT_ws)
{
  __shared__ _Float16 At[128][40];  // 128 x 32 fp16, +8 pad
  __shared__ _Float16 Bt[128][40];
  const int flg = *flag;
  const int tn = blockIdx.x;        // 16 M-tiles of 128 rows
  const int to = blockIdx.y;        // 24 N-tiles of 128 cols over [q|k|v]
  const int mat = to >> 3;          // 0=q 1=k 2=v
  const int o0 = (to & 7) * 128;    // col offset within its matrix
  const unsigned short* W    = (mat == 0) ? Wq : (mat == 1) ? Wk : Wv;
  const unsigned short* bias = (mat == 0) ? bq : (mat == 1) ? bk : bv;
  const float* Wf    = (const float*)W;
  const float* hidf  = (const float*)hidden;
  const float* biasf = (const float*)bias;
  const int tid = threadIdx.x;
  const int lane = tid & 63, wave = tid >> 6;
  const int wm = (wave >> 1) * 64, wn = (wave & 1) * 64;  // 2x2 wave quadrants
  const int lm = lane & 15, lq = lane >> 4;
  const int rs = tid >> 2, sg = tid & 3;                  // staging coords
  f32x4 acc[4][4] = {};

  for (int kc = 0; kc < 1024; kc += 32) {
    __syncthreads();
    if (flg == 0) {
#pragma unroll
      for (int i = 0; i < 2; i++) {
        const int r = rs + i * 64;
        *(f16x8*)(&At[r][sg * 8]) = cvt8_bf(hidden + (size_t)(tn * 128 + r) * 1024 + kc + sg * 8);
        *(f16x8*)(&Bt[r][sg * 8]) = cvt8_bf(W + (size_t)(o0 + r) * 1024 + kc + sg * 8);
      }
    } else {
#pragma unroll
      for (int i = 0; i < 2; i++) {
        const int r = rs + i * 64;
        *(f16x8*)(&At[r][sg * 8]) = cvt8_f32(hidf + (size_t)(tn * 128 + r) * 1024 + kc + sg * 8);
        *(f16x8*)(&Bt[r][sg * 8]) = cvt8_f32(Wf + (size_t)(o0 + r) * 1024 + kc + sg * 8);
      }
    }
    __syncthreads();
    f16x8 af[4], bfr[4];
#pragma unroll
    for (int mt = 0; mt < 4; mt++)
      af[mt] = *(const f16x8*)(&At[wm + mt * 16 + lm][lq * 8]);
#pragma unroll
    for (int nt = 0; nt < 4; nt++)
      bfr[nt] = *(const f16x8*)(&Bt[wn + nt * 16 + lm][lq * 8]);
#pragma unroll
    for (int mt = 0; mt < 4; mt++)
#pragma unroll
      for (int nt = 0; nt < 4; nt++)
        acc[mt][nt] = __builtin_amdgcn_mfma_f32_16x16x32_f16(
            af[mt], bfr[nt], acc[mt][nt], 0, 0, 0);
  }

  // epilogue: C/D layout col=lane&15, row=quad*4+reg
#pragma unroll
  for (int nt = 0; nt < 4; nt++) {
    const int ol = o0 + wn + nt * 16 + lm;   // col within matrix [0,1024)
    const float bias_v = flg ? biasf[ol] : bf2f(bias[ol]);
    const int hh = ol >> 6, dd = ol & 63;
#pragma unroll
    for (int mt = 0; mt < 4; mt++) {
#pragma unroll
      for (int rg = 0; rg < 4; rg++) {
        const int n = tn * 128 + wm + mt * 16 + lq * 4 + rg;  // b*1024+s
        const int b = n >> 10, s = n & 1023;
        const _Float16 hv = h16(acc[mt][nt][rg] + bias_v);
        if (mat == 0)      q_ws[((size_t)(b * 16 + hh) * 1024 + s) * 64 + dd] = hv;
        else if (mat == 1) k_ws[((size_t)(b * 16 + hh) * 1024 + s) * 64 + dd] = hv;
        else               vT_ws[((size_t)(b * 16 + hh) * 64 + dd) * 1024 + s] = hv;
      }
    }
  }
}

// ---------------------------------------------------------------------------
// Kernel 2: fused scores + rel-pos + gumbel double-softmax + PV.
// One block (4 waves) per (b, h, 16-row l-tile). 2048 blocks.
// Scores held fp32 in LDS; probs written back in place as fp16 for PV MFMA.
// ---------------------------------------------------------------------------
#define SROW 1044  // fp32 score row stride (pad: 4*1044 % 32 == 16 -> 2-way, free)

__global__ __launch_bounds__(256) void attn_kernel(
    const _Float16* __restrict__ q_ws, const _Float16* __restrict__ k_ws,
    const _Float16* __restrict__ vT_ws,
    const unsigned short* __restrict__ dist_emb,
    const unsigned short* __restrict__ gumbel_u,
    const unsigned short* __restrict__ mask,
    const int* __restrict__ flag,
    float* __restrict__ out)
{
  __shared__ float Sf[16 * SROW];   // fp32 scores; probs alias as fp16 rows
  __shared__ float Ub[16][84];      // rel-pos gather buffer per r-chunk
  _Float16* Pt = (_Float16*)Sf;     // Pt row i = &Pt[i * 2*SROW]
  const int flg = *flag;
  const int blk = blockIdx.x;
  const int lt = blk & 63;          // l-tile
  const int bh = blk >> 6;
  const int b = bh >> 4, h = bh & 15;
  const int L = lt * 16;
  const _Float16* qp = q_ws + (size_t)bh * 1024 * 64;
  const _Float16* kp = k_ws + (size_t)bh * 1024 * 64;
  const _Float16* vp = vT_ws + (size_t)bh * 64 * 1024;
  const unsigned short* up = gumbel_u + (size_t)bh * 1024 * 1024;
  const float* upf = (const float*)gumbel_u + (size_t)bh * 1024 * 1024;
  const float* def = (const float*)dist_emb;
  const float* maskf = (const float*)mask;
  const int tid = threadIdx.x, wave = tid >> 6, lane = tid & 63;
  const int lm = lane & 15, lq = lane >> 4;

  // Q tile A-fragments (held in registers for the whole block)
  const f16x8 qa0 = *(const f16x8*)(qp + (L + lm) * 64 + lq * 8);
  const f16x8 qa1 = *(const f16x8*)(qp + (L + lm) * 64 + 32 + lq * 8);

  // ---- Phase A: scores = (Q.K^T + Q.E[l-r+1023])/8 + mask -> Sf (fp32) ----
  for (int R = 0; R < 1024; R += 64) {
    f32x4 aqk = {0.f, 0.f, 0.f, 0.f};
    {
      const _Float16* krow = kp + (R + wave * 16 + lm) * 64;
      f16x8 kb0 = *(const f16x8*)(krow + lq * 8);
      f16x8 kb1 = *(const f16x8*)(krow + 32 + lq * 8);
      aqk = __builtin_amdgcn_mfma_f32_16x16x32_f16(qa0, kb0, aqk, 0, 0, 0);
      aqk = __builtin_amdgcn_mfma_f32_16x16x32_f16(qa1, kb1, aqk, 0, 0, 0);
    }
    // U window: E rows [c0, c0+79], rel[l,r] = U[i][i+63-rr]
    const int c0 = L - R + 960;
    for (int t = wave; t < 5; t += 4) {
      int j = c0 + t * 16 + lm;
      if (j > 2046) j = 2046;  // col 79 is never gathered; clamp OOB load only
      f16x8 eb0, eb1;
      if (flg == 0) {
        eb0 = cvt8_bf(dist_emb + (size_t)j * 64 + lq * 8);
        eb1 = cvt8_bf(dist_emb + (size_t)j * 64 + 32 + lq * 8);
      } else {
        eb0 = cvt8_f32(def + (size_t)j * 64 + lq * 8);
        eb1 = cvt8_f32(def + (size_t)j * 64 + 32 + lq * 8);
      }
      f32x4 au = {0.f, 0.f, 0.f, 0.f};
      au = __builtin_amdgcn_mfma_f32_16x16x32_f16(qa0, eb0, au, 0, 0, 0);
      au = __builtin_amdgcn_mfma_f32_16x16x32_f16(qa1, eb1, au, 0, 0, 0);
#pragma unroll
      for (int rg = 0; rg < 4; rg++) Ub[lq * 4 + rg][t * 16 + lm] = au[rg];
    }
    __syncthreads();
    {
      const int rr = wave * 16 + lm;
      const float mval = flg ? maskf[b * 1024 + R + rr] : bf2f(mask[b * 1024 + R + rr]);
#pragma unroll
      for (int rg = 0; rg < 4; rg++) {
        const int i = lq * 4 + rg;
        Sf[i * SROW + R + rr] = (aqk[rg] + Ub[i][i + 63 - rr]) * 0.125f + mval;
      }
    }
    __syncthreads();
  }

  // ---- Phase B: samples = softmax(s+g); t = s+samples; probs = softmax(t).
  // Reads fp32 row into registers, then writes fp16 probs in place (row-local
  // aliasing is safe: all reads of row i complete before its Pt writes).
#pragma unroll 1
  for (int i = wave * 4; i < wave * 4 + 4; i++) {
    const unsigned short* urow = up + (size_t)(L + i) * 1024;
    const float* urowf = upf + (size_t)(L + i) * 1024;
    float sv[16], gv[16];
    float m1 = -1e30f, s1 = 0.f;
#pragma unroll
    for (int c = 0; c < 16; c++) {
      const int r = c * 64 + lane;
      const float s = Sf[i * SROW + r];
      const float u = flg ? urowf[r] : bf2f(urow[r]);
      const float g = -__logf(neglog(u) + 1e-10f);
      sv[c] = s; gv[c] = g;
      const float z = s + g;
      const float mn = fmaxf(m1, z);
      s1 = s1 * __expf(m1 - mn) + __expf(z - mn);
      m1 = mn;
    }
    wred(m1, s1);
    const float is1 = 1.f / s1;
    float m2 = -1e30f, s2 = 0.f;
#pragma unroll
    for (int c = 0; c < 16; c++) {
      const float smp = __expf(sv[c] + gv[c] - m1) * is1;
      const float tt = sv[c] + smp;          // TAU_1 = 1
      sv[c] = tt;
      const float mn = fmaxf(m2, tt);
      s2 = s2 * __expf(m2 - mn) + __expf(tt - mn);
      m2 = mn;
    }
    wred(m2, s2);
    const float is2 = 1.f / s2;
#pragma unroll
    for (int c = 0; c < 16; c++) {
      const float p = __expf(sv[c] - m2) * is2;
      Pt[i * 2 * SROW + c * 64 + lane] = (_Float16)p;   // probs, fp16, in place
    }
  }
  __syncthreads();

  // ---- Phase C: ctx[i][d] = sum_r P[i][r] * V[r][d]  (NT vs V^T) ----
  f32x4 co = {0.f, 0.f, 0.f, 0.f};
  const _Float16* vrow = vp + (wave * 16 + lm) * 1024;  // V^T row d
#pragma unroll 4
  for (int r0 = 0; r0 < 1024; r0 += 32) {
    f16x8 pa = *(const f16x8*)(&Pt[lm * 2 * SROW + r0 + lq * 8]);
    f16x8 vb = *(const f16x8*)(vrow + r0 + lq * 8);
    co = __builtin_amdgcn_mfma_f32_16x16x32_f16(pa, vb, co, 0, 0, 0);
  }
#pragma unroll
  for (int rg = 0; rg < 4; rg++) {
    const int i = lq * 4 + rg;
    out[(size_t)(b * 1024 + L + i) * 1024 + h * 64 + wave * 16 + lm] = co[rg];
  }
}

extern "C" void kernel_launch(void* const* d_in, const int* in_sizes, int n_in,
                              void* d_out, int out_size, void* d_ws, size_t ws_size,
                              hipStream_t stream) {
  const unsigned short* hidden = (const unsigned short*)d_in[0];
  const unsigned short* mask   = (const unsigned short*)d_in[1];
  const unsigned short* gum    = (const unsigned short*)d_in[2];
  const unsigned short* Wq     = (const unsigned short*)d_in[3];
  const unsigned short* bq     = (const unsigned short*)d_in[4];
  const unsigned short* Wk     = (const unsigned short*)d_in[5];
  const unsigned short* bk     = (const unsigned short*)d_in[6];
  const unsigned short* Wv     = (const unsigned short*)d_in[7];
  const unsigned short* bv     = (const unsigned short*)d_in[8];
  const unsigned short* de     = (const unsigned short*)d_in[9];

  int* flag = (int*)d_ws;                                     // 256 B header
  _Float16* q_ws  = (_Float16*)((char*)d_ws + 256);           // 4 MB [B,H,S,64]
  _Float16* k_ws  = q_ws + (size_t)2 * 1024 * 1024;           // 4 MB [B,H,S,64]
  _Float16* vT_ws = k_ws + (size_t)2 * 1024 * 1024;           // 4 MB [B,H,64,S]
  float* out = (float*)d_out;                                 // fp32 output!

  detect_dtype<<<1, 64, 0, stream>>>(gum, flag);
  qkv_gemm<<<dim3(16, 24), 256, 0, stream>>>(hidden, Wq, bq, Wk, bk, Wv, bv,
                                             flag, q_ws, k_ws, vT_ws);
  attn_kernel<<<2048, 256, 0, stream>>>(q_ws, k_ws, vT_ws, de, gum, mask, flag, out);
}

// Round 4
// 380.693 us; speedup vs baseline: 1.4419x; 1.4419x over previous
//
#include <hip/hip_runtime.h>
#include <hip/hip_bf16.h>

typedef _Float16 f16x8 __attribute__((ext_vector_type(8)));
typedef _Float16 f16x4 __attribute__((ext_vector_type(4)));
typedef float f32x4 __attribute__((ext_vector_type(4)));
typedef int i32x4 __attribute__((ext_vector_type(4)));

__device__ __forceinline__ float bf2f(unsigned short u) {
  union { unsigned int i; float f; } x; x.i = ((unsigned int)u) << 16; return x.f;
}
// clamp-to-finite fp16 convert: any upstream bug shows finite, not NaN
__device__ __forceinline__ _Float16 h16(float f) {
  return (_Float16)fminf(fmaxf(f, -60000.f), 60000.f);
}

// accurate -log(u): series for u near 1 (1-u exact by Sterbenz there)
__device__ __forceinline__ float neglog(float u) {
  if (u > 0.99f) {
    const float d = 1.0f - u;
    return d + 0.5f * d * d + (1.0f / 3.0f) * d * d * d;
  }
  return -__logf(u);
}

// plain butterfly sum across 64 lanes
__device__ __forceinline__ float wsum(float v) {
#pragma unroll
  for (int off = 1; off < 64; off <<= 1) v += __shfl_xor(v, off, 64);
  return v;
}

__device__ __forceinline__ f16x8 cvt8_bf(const unsigned short* p) {
  union { i32x4 v; unsigned short u[8]; } ld;
  ld.v = *(const i32x4*)p;
  f16x8 r;
#pragma unroll
  for (int j = 0; j < 8; j++) r[j] = h16(bf2f(ld.u[j]));
  return r;
}
__device__ __forceinline__ f16x8 cvt8_f32(const float* p) {
  f32x4 a = *(const f32x4*)p;
  f32x4 b = *(const f32x4*)(p + 4);
  f16x8 r;
#pragma unroll
  for (int j = 0; j < 4; j++) { r[j] = h16(a[j]); r[4 + j] = h16(b[j]); }
  return r;
}

// ---------------------------------------------------------------------------
// Kernel 0: input dtype detector (gumbel_u in (1e-6,1-1e-6)).
// flag: 0 = bf16 inputs, 1 = fp32 inputs.
// ---------------------------------------------------------------------------
__global__ void detect_dtype(const unsigned short* __restrict__ g, int* __restrict__ flag) {
  const int lane = threadIdx.x;
  const float f = bf2f(g[lane * 2]);
  const bool ok = (f >= 8e-7f) && (f <= 1.0f);
  const unsigned long long m = __ballot(ok);
  if (lane == 0) *flag = (m == ~0ull) ? 0 : 1;
}

// ---------------------------------------------------------------------------
// Kernel 0b: convert hidden + Wq/Wk/Wv to fp16 once (removes all conversion
// VALU from the GEMM staging loop). dst: [hid 2M | Wq 1M | Wk 1M | Wv 1M].
// ---------------------------------------------------------------------------
__global__ __launch_bounds__(256) void cvt_inputs(
    const void* __restrict__ h, const void* __restrict__ wq,
    const void* __restrict__ wk, const void* __restrict__ wv,
    const int* __restrict__ flag, _Float16* __restrict__ dst)
{
  const int y = blockIdx.y;
  const int n = (y == 0) ? (2 * 1024 * 1024) : (1024 * 1024);
  const int idx = (blockIdx.x * 256 + threadIdx.x) * 4;
  if (idx >= n) return;
  const void* src = (y == 0) ? h : (y == 1) ? wq : (y == 2) ? wk : wv;
  const size_t base = (y == 0) ? 0 : (size_t)(2 * 1024 * 1024) + (size_t)(y - 1) * 1024 * 1024;
  f16x4 o;
  if (*flag) {
    f32x4 v = *(const f32x4*)((const float*)src + idx);
#pragma unroll
    for (int j = 0; j < 4; j++) o[j] = h16(v[j]);
  } else {
    union { unsigned long long q; unsigned short u[4]; } ld;
    ld.q = *(const unsigned long long*)((const unsigned short*)src + idx);
#pragma unroll
    for (int j = 0; j < 4; j++) o[j] = h16(bf2f(ld.u[j]));
  }
  *(f16x4*)(dst + base + idx) = o;
}

// ---------------------------------------------------------------------------
// Kernel 1: QKV projection on pre-converted fp16. NT gemm 2048 x 3072 x 1024.
// q,k stored fp16 [B,H,S,64]; v stored transposed fp16 [B,H,64,S].
// ---------------------------------------------------------------------------
__global__ __launch_bounds__(256) void qkv_gemm(
    const _Float16* __restrict__ cvt,   // [hid | Wq | Wk | Wv]
    const unsigned short* __restrict__ bq, const unsigned short* __restrict__ bk,
    const unsigned short* __restrict__ bv,
    const int* __restrict__ flag,
    _Float16* __restrict__ q_ws, _Float16* __restrict__ k_ws,
    _Float16* __restrict__ vT_ws)
{
  __shared__ _Float16 At[128][44];  // 128 x 32 fp16, +12 pad (breaks 8-way)
  __shared__ _Float16 Bt[128][44];
  const int flg = *flag;
  const int tn = blockIdx.x;        // 16 M-tiles of 128 rows
  const int to = blockIdx.y;        // 24 N-tiles of 128 cols over [q|k|v]
  const int mat = to >> 3;          // 0=q 1=k 2=v
  const int o0 = (to & 7) * 128;
  const _Float16* hid16 = cvt;
  const _Float16* W16 = cvt + (size_t)(2 * 1024 * 1024) + (size_t)mat * 1024 * 1024;
  const unsigned short* bias = (mat == 0) ? bq : (mat == 1) ? bk : bv;
  const float* biasf = (const float*)bias;
  const int tid = threadIdx.x;
  const int lane = tid & 63, wave = tid >> 6;
  const int wm = (wave >> 1) * 64, wn = (wave & 1) * 64;
  const int lm = lane & 15, lq = lane >> 4;
  const int rs = tid >> 2, sg = tid & 3;
  f32x4 acc[4][4] = {};

  for (int kc = 0; kc < 1024; kc += 32) {
    __syncthreads();
#pragma unroll
    for (int i = 0; i < 2; i++) {
      const int r = rs + i * 64;
      *(i32x4*)(&At[r][sg * 8]) =
          *(const i32x4*)(hid16 + (size_t)(tn * 128 + r) * 1024 + kc + sg * 8);
      *(i32x4*)(&Bt[r][sg * 8]) =
          *(const i32x4*)(W16 + (size_t)(o0 + r) * 1024 + kc + sg * 8);
    }
    __syncthreads();
    f16x8 af[4], bfr[4];
#pragma unroll
    for (int mt = 0; mt < 4; mt++)
      af[mt] = *(const f16x8*)(&At[wm + mt * 16 + lm][lq * 8]);
#pragma unroll
    for (int nt = 0; nt < 4; nt++)
      bfr[nt] = *(const f16x8*)(&Bt[wn + nt * 16 + lm][lq * 8]);
#pragma unroll
    for (int mt = 0; mt < 4; mt++)
#pragma unroll
      for (int nt = 0; nt < 4; nt++)
        acc[mt][nt] = __builtin_amdgcn_mfma_f32_16x16x32_f16(
            af[mt], bfr[nt], acc[mt][nt], 0, 0, 0);
  }

  // epilogue: C/D layout col=lane&15, row=quad*4+reg
#pragma unroll
  for (int nt = 0; nt < 4; nt++) {
    const int ol = o0 + wn + nt * 16 + lm;
    const float bias_v = flg ? biasf[ol] : bf2f(bias[ol]);
    const int hh = ol >> 6, dd = ol & 63;
#pragma unroll
    for (int mt = 0; mt < 4; mt++) {
#pragma unroll
      for (int rg = 0; rg < 4; rg++) {
        const int n = tn * 128 + wm + mt * 16 + lq * 4 + rg;  // b*1024+s
        const int b = n >> 10, s = n & 1023;
        const _Float16 hv = h16(acc[mt][nt][rg] + bias_v);
        if (mat == 0)      q_ws[((size_t)(b * 16 + hh) * 1024 + s) * 64 + dd] = hv;
        else if (mat == 1) k_ws[((size_t)(b * 16 + hh) * 1024 + s) * 64 + dd] = hv;
        else               vT_ws[((size_t)(b * 16 + hh) * 64 + dd) * 1024 + s] = hv;
      }
    }
  }
}

// ---------------------------------------------------------------------------
// Kernel 2: fused scores + rel-pos + gumbel double-softmax + PV.
// One block (4 waves) per (b, h, 16-row l-tile). 2048 blocks, 4 blocks/CU.
// Scores fp16 in LDS (39 KB total); max-free double softmax (exp bounded:
// z <= s+16, t <= s+1, both safely in fp32 range).
// ---------------------------------------------------------------------------
#define ROWH 1040  // fp16 score row stride (8-elem aligned; 8-bank row skew)

__global__ __launch_bounds__(256, 4) void attn_kernel(
    const _Float16* __restrict__ q_ws, const _Float16* __restrict__ k_ws,
    const _Float16* __restrict__ vT_ws,
    const unsigned short* __restrict__ dist_emb,
    const unsigned short* __restrict__ gumbel_u,
    const unsigned short* __restrict__ mask,
    const int* __restrict__ flag,
    float* __restrict__ out)
{
  __shared__ _Float16 St[16 * ROWH];  // scores -> probs in place (fp16)
  __shared__ float Ub[16][84];        // rel-pos gather buffer per r-chunk
  const int flg = *flag;
  const int blk = blockIdx.x;
  const int lt = blk & 63;
  const int bh = blk >> 6;
  const int b = bh >> 4, h = bh & 15;
  const int L = lt * 16;
  const _Float16* qp = q_ws + (size_t)bh * 1024 * 64;
  const _Float16* kp = k_ws + (size_t)bh * 1024 * 64;
  const _Float16* vp = vT_ws + (size_t)bh * 64 * 1024;
  const unsigned short* up = gumbel_u + (size_t)bh * 1024 * 1024;
  const float* upf = (const float*)gumbel_u + (size_t)bh * 1024 * 1024;
  const float* def = (const float*)dist_emb;
  const float* maskf = (const float*)mask;
  const int tid = threadIdx.x, wave = tid >> 6, lane = tid & 63;
  const int lm = lane & 15, lq = lane >> 4;

  // Q tile A-fragments held for the whole block
  const f16x8 qa0 = *(const f16x8*)(qp + (L + lm) * 64 + lq * 8);
  const f16x8 qa1 = *(const f16x8*)(qp + (L + lm) * 64 + 32 + lq * 8);

  // ---- Phase A: scores = (Q.K^T + Q.E[l-r+1023])/8 + mask -> St (fp16) ----
  for (int R = 0; R < 1024; R += 64) {
    f32x4 aqk = {0.f, 0.f, 0.f, 0.f};
    {
      const _Float16* krow = kp + (R + wave * 16 + lm) * 64;
      f16x8 kb0 = *(const f16x8*)(krow + lq * 8);
      f16x8 kb1 = *(const f16x8*)(krow + 32 + lq * 8);
      aqk = __builtin_amdgcn_mfma_f32_16x16x32_f16(qa0, kb0, aqk, 0, 0, 0);
      aqk = __builtin_amdgcn_mfma_f32_16x16x32_f16(qa1, kb1, aqk, 0, 0, 0);
    }
    // U window: E rows [c0, c0+79], rel[l,r] = U[i][i+63-rr]
    const int c0 = L - R + 960;
    for (int t = wave; t < 5; t += 4) {
      int j = c0 + t * 16 + lm;
      if (j > 2046) j = 2046;  // col 79 never gathered; clamp OOB load only
      f16x8 eb0, eb1;
      if (flg == 0) {
        eb0 = cvt8_bf(dist_emb + (size_t)j * 64 + lq * 8);
        eb1 = cvt8_bf(dist_emb + (size_t)j * 64 + 32 + lq * 8);
      } else {
        eb0 = cvt8_f32(def + (size_t)j * 64 + lq * 8);
        eb1 = cvt8_f32(def + (size_t)j * 64 + 32 + lq * 8);
      }
      f32x4 au = {0.f, 0.f, 0.f, 0.f};
      au = __builtin_amdgcn_mfma_f32_16x16x32_f16(qa0, eb0, au, 0, 0, 0);
      au = __builtin_amdgcn_mfma_f32_16x16x32_f16(qa1, eb1, au, 0, 0, 0);
#pragma unroll
      for (int rg = 0; rg < 4; rg++) Ub[lq * 4 + rg][t * 16 + lm] = au[rg];
    }
    __syncthreads();
    {
      const int rr = wave * 16 + lm;
      const float mval = flg ? maskf[b * 1024 + R + rr] : bf2f(mask[b * 1024 + R + rr]);
#pragma unroll
      for (int rg = 0; rg < 4; rg++) {
        const int i = lq * 4 + rg;
        St[i * ROWH + R + rr] = h16((aqk[rg] + Ub[i][i + 63 - rr]) * 0.125f + mval);
      }
    }
    __syncthreads();
  }

  // ---- Phase B: max-free double softmax.
  //   num1 = exp(s)/( -log(u+eps) + eps ); samples = num1/sum(num1)
  //   num2 = exp(s + samples);             probs   = num2/sum(num2)
#pragma unroll 1
  for (int i = wave * 4; i < wave * 4 + 4; i++) {
    float uv[16];
    if (flg) {
      const float* urf = upf + (size_t)(L + i) * 1024 + lane;
#pragma unroll
      for (int c = 0; c < 16; c++) uv[c] = urf[c * 64];
    } else {
      const unsigned short* ur = up + (size_t)(L + i) * 1024 + lane;
#pragma unroll
      for (int c = 0; c < 16; c++) uv[c] = bf2f(ur[c * 64]);
    }
    float num1[16];
    float s1 = 0.f;
#pragma unroll
    for (int c = 0; c < 16; c++) {
      const float s = (float)St[i * ROWH + c * 64 + lane];
      const float nl = neglog(uv[c] + 1e-10f) + 1e-10f;
      num1[c] = __expf(s) * __builtin_amdgcn_rcpf(nl);
      s1 += num1[c];
    }
    s1 = wsum(s1);
    const float is1 = __builtin_amdgcn_rcpf(s1);
    float num2[16];
    float s2 = 0.f;
#pragma unroll
    for (int c = 0; c < 16; c++) {
      const float s = (float)St[i * ROWH + c * 64 + lane];
      num2[c] = __expf(s + num1[c] * is1);   // TAU_1 = 1
      s2 += num2[c];
    }
    s2 = wsum(s2);
    const float is2 = __builtin_amdgcn_rcpf(s2);
#pragma unroll
    for (int c = 0; c < 16; c++)
      St[i * ROWH + c * 64 + lane] = (_Float16)(num2[c] * is2);
  }
  __syncthreads();

  // ---- Phase C: ctx[i][d] = sum_r P[i][r] * V[r][d]  (NT vs V^T) ----
  f32x4 co = {0.f, 0.f, 0.f, 0.f};
  const _Float16* vrow = vp + (wave * 16 + lm) * 1024;  // V^T row d
#pragma unroll 4
  for (int r0 = 0; r0 < 1024; r0 += 32) {
    f16x8 pa = *(const f16x8*)(&St[lm * ROWH + r0 + lq * 8]);
    f16x8 vb = *(const f16x8*)(vrow + r0 + lq * 8);
    co = __builtin_amdgcn_mfma_f32_16x16x32_f16(pa, vb, co, 0, 0, 0);
  }
#pragma unroll
  for (int rg = 0; rg < 4; rg++) {
    const int i = lq * 4 + rg;
    out[(size_t)(b * 1024 + L + i) * 1024 + h * 64 + wave * 16 + lm] = co[rg];
  }
}

extern "C" void kernel_launch(void* const* d_in, const int* in_sizes, int n_in,
                              void* d_out, int out_size, void* d_ws, size_t ws_size,
                              hipStream_t stream) {
  const unsigned short* hidden = (const unsigned short*)d_in[0];
  const unsigned short* mask   = (const unsigned short*)d_in[1];
  const unsigned short* gum    = (const unsigned short*)d_in[2];
  const unsigned short* Wq     = (const unsigned short*)d_in[3];
  const unsigned short* bq     = (const unsigned short*)d_in[4];
  const unsigned short* Wk     = (const unsigned short*)d_in[5];
  const unsigned short* bk     = (const unsigned short*)d_in[6];
  const unsigned short* Wv     = (const unsigned short*)d_in[7];
  const unsigned short* bv     = (const unsigned short*)d_in[8];
  const unsigned short* de     = (const unsigned short*)d_in[9];

  int* flag = (int*)d_ws;                                        // 256 B
  _Float16* cvt16 = (_Float16*)((char*)d_ws + 256);              // 10 MB
  _Float16* q_ws  = cvt16 + (size_t)5 * 1024 * 1024;             // 4 MB
  _Float16* k_ws  = q_ws + (size_t)2 * 1024 * 1024;              // 4 MB
  _Float16* vT_ws = k_ws + (size_t)2 * 1024 * 1024;              // 4 MB
  float* out = (float*)d_out;

  detect_dtype<<<1, 64, 0, stream>>>(gum, flag);
  cvt_inputs<<<dim3(2048, 4), 256, 0, stream>>>(hidden, Wq, Wk, Wv, flag, cvt16);
  qkv_gemm<<<dim3(16, 24), 256, 0, stream>>>(cvt16, bq, bk, bv, flag,
                                             q_ws, k_ws, vT_ws);
  attn_kernel<<<2048, 256, 0, stream>>>(q_ws, k_ws, vT_ws, de, gum, mask, flag, out);
}

// Round 5
// 368.304 us; speedup vs baseline: 1.4904x; 1.0336x over previous
//
#include <hip/hip_runtime.h>
#include <hip/hip_bf16.h>

typedef _Float16 f16x8 __attribute__((ext_vector_type(8)));
typedef _Float16 f16x4 __attribute__((ext_vector_type(4)));
typedef float f32x4 __attribute__((ext_vector_type(4)));
typedef int i32x4 __attribute__((ext_vector_type(4)));

__device__ __forceinline__ float bf2f(unsigned short u) {
  union { unsigned int i; float f; } x; x.i = ((unsigned int)u) << 16; return x.f;
}
// clamp-to-finite fp16 convert: any upstream bug shows finite, not NaN
__device__ __forceinline__ _Float16 h16(float f) {
  return (_Float16)fminf(fmaxf(f, -60000.f), 60000.f);
}

// accurate -log(u): series for u near 1 (1-u exact by Sterbenz there)
__device__ __forceinline__ float neglog(float u) {
  if (u > 0.99f) {
    const float d = 1.0f - u;
    return d + 0.5f * d * d + (1.0f / 3.0f) * d * d * d;
  }
  return -__logf(u);
}

// plain butterfly sum across 64 lanes
__device__ __forceinline__ float wsum(float v) {
#pragma unroll
  for (int off = 1; off < 64; off <<= 1) v += __shfl_xor(v, off, 64);
  return v;
}

__device__ __forceinline__ f16x8 cvt8_bf(const unsigned short* p) {
  union { i32x4 v; unsigned short u[8]; } ld;
  ld.v = *(const i32x4*)p;
  f16x8 r;
#pragma unroll
  for (int j = 0; j < 8; j++) r[j] = h16(bf2f(ld.u[j]));
  return r;
}
__device__ __forceinline__ f16x8 cvt8_f32(const float* p) {
  f32x4 a = *(const f32x4*)p;
  f32x4 b = *(const f32x4*)(p + 4);
  f16x8 r;
#pragma unroll
  for (int j = 0; j < 4; j++) { r[j] = h16(a[j]); r[4 + j] = h16(b[j]); }
  return r;
}

// ---------------------------------------------------------------------------
// Kernel 0: input dtype detector (gumbel_u in (1e-6,1-1e-6)).
// flag: 0 = bf16 inputs, 1 = fp32 inputs.
// ---------------------------------------------------------------------------
__global__ void detect_dtype(const unsigned short* __restrict__ g, int* __restrict__ flag) {
  const int lane = threadIdx.x;
  const float f = bf2f(g[lane * 2]);
  const bool ok = (f >= 8e-7f) && (f <= 1.0f);
  const unsigned long long m = __ballot(ok);
  if (lane == 0) *flag = (m == ~0ull) ? 0 : 1;
}

// ---------------------------------------------------------------------------
// Kernel 0b: convert hidden + Wq/Wk/Wv to fp16 once.
// dst: [hid 2M | Wq 1M | Wk 1M | Wv 1M] halves.
// ---------------------------------------------------------------------------
__global__ __launch_bounds__(256) void cvt_inputs(
    const void* __restrict__ h, const void* __restrict__ wq,
    const void* __restrict__ wk, const void* __restrict__ wv,
    const int* __restrict__ flag, _Float16* __restrict__ dst)
{
  const int y = blockIdx.y;
  const int n = (y == 0) ? (2 * 1024 * 1024) : (1024 * 1024);
  const int idx = (blockIdx.x * 256 + threadIdx.x) * 4;
  if (idx >= n) return;
  const void* src = (y == 0) ? h : (y == 1) ? wq : (y == 2) ? wk : wv;
  const size_t base = (y == 0) ? 0 : (size_t)(2 * 1024 * 1024) + (size_t)(y - 1) * 1024 * 1024;
  f16x4 o;
  if (*flag) {
    f32x4 v = *(const f32x4*)((const float*)src + idx);
#pragma unroll
    for (int j = 0; j < 4; j++) o[j] = h16(v[j]);
  } else {
    union { unsigned long long q; unsigned short u[4]; } ld;
    ld.q = *(const unsigned long long*)((const unsigned short*)src + idx);
#pragma unroll
    for (int j = 0; j < 4; j++) o[j] = h16(bf2f(ld.u[j]));
  }
  *(f16x4*)(dst + base + idx) = o;
}

// ---------------------------------------------------------------------------
// Kernel 1: QKV projection on pre-converted fp16. NT gemm 2048 x 3072 x 1024.
// 64x128 tiles, BK=64 -> 768 blocks (3/CU) for latency hiding.
// q,k,v all stored fp16 [B,H,S,64] (v transposed by a separate kernel).
// ---------------------------------------------------------------------------
__global__ __launch_bounds__(256) void qkv_gemm(
    const _Float16* __restrict__ cvt,   // [hid | Wq | Wk | Wv]
    const unsigned short* __restrict__ bq, const unsigned short* __restrict__ bk,
    const unsigned short* __restrict__ bv,
    const int* __restrict__ flag,
    _Float16* __restrict__ q_ws, _Float16* __restrict__ k_ws,
    _Float16* __restrict__ v_ws)
{
  __shared__ _Float16 At[64][72];   // 64 x 64 fp16, +8 pad
  __shared__ _Float16 Bt[128][72];  // 128 x 64 fp16, +8 pad
  const int flg = *flag;
  const int tn = blockIdx.x;        // 32 M-tiles of 64 rows
  const int to = blockIdx.y;        // 24 N-tiles of 128 cols over [q|k|v]
  const int mat = to >> 3;          // 0=q 1=k 2=v
  const int o0 = (to & 7) * 128;
  const _Float16* hid16 = cvt;
  const _Float16* W16 = cvt + (size_t)(2 * 1024 * 1024) + (size_t)mat * 1024 * 1024;
  const unsigned short* bias = (mat == 0) ? bq : (mat == 1) ? bk : bv;
  const float* biasf = (const float*)bias;
  const int tid = threadIdx.x;
  const int lane = tid & 63, wave = tid >> 6;
  const int wm = (wave >> 1) * 32, wn = (wave & 1) * 64;  // 2x2 quadrants 32x64
  const int lm = lane & 15, lq = lane >> 4;
  f32x4 acc[2][4] = {};

  for (int kc = 0; kc < 1024; kc += 64) {
    __syncthreads();
#pragma unroll
    for (int i = 0; i < 2; i++) {  // A: 64 rows x 8 chunks of 16B
      const int cid = i * 256 + tid;
      const int r = cid >> 3, c8 = cid & 7;
      *(i32x4*)(&At[r][c8 * 8]) =
          *(const i32x4*)(hid16 + (size_t)(tn * 64 + r) * 1024 + kc + c8 * 8);
    }
#pragma unroll
    for (int i = 0; i < 4; i++) {  // B: 128 rows x 8 chunks of 16B
      const int cid = i * 256 + tid;
      const int r = cid >> 3, c8 = cid & 7;
      *(i32x4*)(&Bt[r][c8 * 8]) =
          *(const i32x4*)(W16 + (size_t)(o0 + r) * 1024 + kc + c8 * 8);
    }
    __syncthreads();
    f16x8 af[2][2], bfr[4][2];
#pragma unroll
    for (int mt = 0; mt < 2; mt++)
#pragma unroll
      for (int k2 = 0; k2 < 2; k2++)
        af[mt][k2] = *(const f16x8*)(&At[wm + mt * 16 + lm][k2 * 32 + lq * 8]);
#pragma unroll
    for (int nt = 0; nt < 4; nt++)
#pragma unroll
      for (int k2 = 0; k2 < 2; k2++)
        bfr[nt][k2] = *(const f16x8*)(&Bt[wn + nt * 16 + lm][k2 * 32 + lq * 8]);
#pragma unroll
    for (int mt = 0; mt < 2; mt++)
#pragma unroll
      for (int nt = 0; nt < 4; nt++)
#pragma unroll
        for (int k2 = 0; k2 < 2; k2++)
          acc[mt][nt] = __builtin_amdgcn_mfma_f32_16x16x32_f16(
              af[mt][k2], bfr[nt][k2], acc[mt][nt], 0, 0, 0);
  }

  // epilogue: C/D layout col=lane&15, row=quad*4+reg
  _Float16* dst = (mat == 0) ? q_ws : (mat == 1) ? k_ws : v_ws;
#pragma unroll
  for (int nt = 0; nt < 4; nt++) {
    const int ol = o0 + wn + nt * 16 + lm;
    const float bias_v = flg ? biasf[ol] : bf2f(bias[ol]);
    const int hh = ol >> 6, dd = ol & 63;
#pragma unroll
    for (int mt = 0; mt < 2; mt++) {
#pragma unroll
      for (int rg = 0; rg < 4; rg++) {
        const int n = tn * 64 + wm + mt * 16 + lq * 4 + rg;  // b*1024+s
        const int b = n >> 10, s = n & 1023;
        dst[((size_t)(b * 16 + hh) * 1024 + s) * 64 + dd] = h16(acc[mt][nt][rg] + bias_v);
      }
    }
  }
}

// ---------------------------------------------------------------------------
// Kernel 1b: transpose v [bh][s][64] -> vT [bh][64][s] via LDS 64x64 tiles.
// Stride-66 LDS layout: writes (dword) and column reads both conflict-free.
// ---------------------------------------------------------------------------
__global__ __launch_bounds__(256) void transpose_v(
    const _Float16* __restrict__ v_ws, _Float16* __restrict__ vT_ws)
{
  __shared__ unsigned short Tt[64 * 66];
  const int st = blockIdx.x;   // 16 s-tiles
  const int bh = blockIdx.y;   // 32
  const int tid = threadIdx.x;
  const unsigned short* src = (const unsigned short*)(v_ws + (size_t)bh * 65536);
#pragma unroll
  for (int i = 0; i < 2; i++) {
    const int cid = i * 256 + tid;
    const int r = cid >> 3, c8 = cid & 7;   // row in tile, 8-half chunk
    union { i32x4 v; unsigned int w[4]; } ld;
    ld.v = *(const i32x4*)(src + (size_t)(st * 64 + r) * 64 + c8 * 8);
#pragma unroll
    for (int w = 0; w < 4; w++)
      *(unsigned int*)(&Tt[r * 66 + c8 * 8 + w * 2]) = ld.w[w];
  }
  __syncthreads();
  const int d = tid >> 2, sc = (tid & 3) * 16;
  unsigned short us[16];
#pragma unroll
  for (int j = 0; j < 16; j++) us[j] = Tt[(sc + j) * 66 + d];
  unsigned short* dst = (unsigned short*)(vT_ws + (size_t)bh * 65536 + (size_t)d * 1024 + st * 64 + sc);
#pragma unroll
  for (int w = 0; w < 4; w++)
    *(unsigned long long*)(dst + w * 4) = *(unsigned long long*)(us + w * 4);
}

// ---------------------------------------------------------------------------
// Kernel 2: fused scores + rel-pos + gumbel double-softmax + PV.
// One block (4 waves) per (b, h, 16-row l-tile). 2048 blocks, 4 blocks/CU.
// ---------------------------------------------------------------------------
#define ROWH 1048  // fp16 score row stride (16B-aligned; phase-C b128 min-conflict)

__global__ __launch_bounds__(256, 4) void attn_kernel(
    const _Float16* __restrict__ q_ws, const _Float16* __restrict__ k_ws,
    const _Float16* __restrict__ vT_ws,
    const unsigned short* __restrict__ dist_emb,
    const unsigned short* __restrict__ gumbel_u,
    const unsigned short* __restrict__ mask,
    const int* __restrict__ flag,
    float* __restrict__ out)
{
  __shared__ _Float16 St[16 * ROWH];  // scores -> probs in place (fp16)
  __shared__ float Ub[16][84];        // rel-pos gather buffer per r-chunk
  const int flg = *flag;
  const int blk = blockIdx.x;
  const int lt = blk & 63;
  const int bh = blk >> 6;
  const int b = bh >> 4, h = bh & 15;
  const int L = lt * 16;
  const _Float16* qp = q_ws + (size_t)bh * 65536;
  const _Float16* kp = k_ws + (size_t)bh * 65536;
  const _Float16* vp = vT_ws + (size_t)bh * 65536;
  const unsigned short* up = gumbel_u + (size_t)bh * 1024 * 1024;
  const float* upf = (const float*)gumbel_u + (size_t)bh * 1024 * 1024;
  const float* def = (const float*)dist_emb;
  const float* maskf = (const float*)mask;
  const int tid = threadIdx.x, wave = tid >> 6, lane = tid & 63;
  const int lm = lane & 15, lq = lane >> 4;

  // Q tile A-fragments held for the whole block
  const f16x8 qa0 = *(const f16x8*)(qp + (L + lm) * 64 + lq * 8);
  const f16x8 qa1 = *(const f16x8*)(qp + (L + lm) * 64 + 32 + lq * 8);

  // ---- Phase A: scores = (Q.K^T + Q.E[l-r+1023])/8 + mask -> St (fp16) ----
  for (int R = 0; R < 1024; R += 64) {
    f32x4 aqk = {0.f, 0.f, 0.f, 0.f};
    {
      const _Float16* krow = kp + (R + wave * 16 + lm) * 64;
      f16x8 kb0 = *(const f16x8*)(krow + lq * 8);
      f16x8 kb1 = *(const f16x8*)(krow + 32 + lq * 8);
      aqk = __builtin_amdgcn_mfma_f32_16x16x32_f16(qa0, kb0, aqk, 0, 0, 0);
      aqk = __builtin_amdgcn_mfma_f32_16x16x32_f16(qa1, kb1, aqk, 0, 0, 0);
    }
    // U window: E rows [c0, c0+79], rel[l,r] = U[i][i+63-rr]
    const int c0 = L - R + 960;
    for (int t = wave; t < 5; t += 4) {
      int j = c0 + t * 16 + lm;
      if (j > 2046) j = 2046;  // col 79 never gathered; clamp OOB load only
      f16x8 eb0, eb1;
      if (flg == 0) {
        eb0 = cvt8_bf(dist_emb + (size_t)j * 64 + lq * 8);
        eb1 = cvt8_bf(dist_emb + (size_t)j * 64 + 32 + lq * 8);
      } else {
        eb0 = cvt8_f32(def + (size_t)j * 64 + lq * 8);
        eb1 = cvt8_f32(def + (size_t)j * 64 + 32 + lq * 8);
      }
      f32x4 au = {0.f, 0.f, 0.f, 0.f};
      au = __builtin_amdgcn_mfma_f32_16x16x32_f16(qa0, eb0, au, 0, 0, 0);
      au = __builtin_amdgcn_mfma_f32_16x16x32_f16(qa1, eb1, au, 0, 0, 0);
#pragma unroll
      for (int rg = 0; rg < 4; rg++) Ub[lq * 4 + rg][t * 16 + lm] = au[rg];
    }
    __syncthreads();
    {
      const int rr = wave * 16 + lm;
      const float mval = flg ? maskf[b * 1024 + R + rr] : bf2f(mask[b * 1024 + R + rr]);
#pragma unroll
      for (int rg = 0; rg < 4; rg++) {
        const int i = lq * 4 + rg;
        St[i * ROWH + R + rr] = h16((aqk[rg] + Ub[i][i + 63 - rr]) * 0.125f + mval);
      }
    }
    __syncthreads();
  }

  // ---- Phase B: max-free double softmax, vectorized runs.
  // Lane owns elements e = c*256 + lane*4 + j (c,j in 0..3): b64 LDS +
  // dwordx4 global, minimum bank aliasing.
#pragma unroll 1
  for (int i = wave * 4; i < wave * 4 + 4; i++) {
    float uv[4][4];
    if (flg) {
      const float* urf = upf + (size_t)(L + i) * 1024 + lane * 4;
#pragma unroll
      for (int c = 0; c < 4; c++) *(f32x4*)uv[c] = *(const f32x4*)(urf + c * 256);
    } else {
      const unsigned short* ur = up + (size_t)(L + i) * 1024 + lane * 4;
#pragma unroll
      for (int c = 0; c < 4; c++) {
        union { unsigned long long q; unsigned short u[4]; } ld;
        ld.q = *(const unsigned long long*)(ur + c * 256);
#pragma unroll
        for (int j = 0; j < 4; j++) uv[c][j] = bf2f(ld.u[j]);
      }
    }
    f16x4 sh[4];
#pragma unroll
    for (int c = 0; c < 4; c++)
      sh[c] = *(const f16x4*)(&St[i * ROWH + c * 256 + lane * 4]);
    float num1[4][4];
    float s1 = 0.f;
#pragma unroll
    for (int c = 0; c < 4; c++)
#pragma unroll
      for (int j = 0; j < 4; j++) {
        const float s = (float)sh[c][j];
        const float nl = neglog(uv[c][j] + 1e-10f) + 1e-10f;
        num1[c][j] = __expf(s) * __builtin_amdgcn_rcpf(nl);
        s1 += num1[c][j];
      }
    s1 = wsum(s1);
    const float is1 = __builtin_amdgcn_rcpf(s1);
    float num2[4][4];
    float s2 = 0.f;
#pragma unroll
    for (int c = 0; c < 4; c++)
#pragma unroll
      for (int j = 0; j < 4; j++) {
        num2[c][j] = __expf((float)sh[c][j] + num1[c][j] * is1);  // TAU_1 = 1
        s2 += num2[c][j];
      }
    s2 = wsum(s2);
    const float is2 = __builtin_amdgcn_rcpf(s2);
#pragma unroll
    for (int c = 0; c < 4; c++) {
      f16x4 pw;
#pragma unroll
      for (int j = 0; j < 4; j++) pw[j] = (_Float16)(num2[c][j] * is2);
      *(f16x4*)(&St[i * ROWH + c * 256 + lane * 4]) = pw;
    }
  }
  __syncthreads();

  // ---- Phase C: ctx[i][d] = sum_r P[i][r] * V[r][d]  (NT vs V^T) ----
  f32x4 co = {0.f, 0.f, 0.f, 0.f};
  const _Float16* vrow = vp + (wave * 16 + lm) * 1024;  // V^T row d
#pragma unroll 4
  for (int r0 = 0; r0 < 1024; r0 += 32) {
    f16x8 pa = *(const f16x8*)(&St[lm * ROWH + r0 + lq * 8]);
    f16x8 vb = *(const f16x8*)(vrow + r0 + lq * 8);
    co = __builtin_amdgcn_mfma_f32_16x16x32_f16(pa, vb, co, 0, 0, 0);
  }
#pragma unroll
  for (int rg = 0; rg < 4; rg++) {
    const int i = lq * 4 + rg;
    out[(size_t)(b * 1024 + L + i) * 1024 + h * 64 + wave * 16 + lm] = co[rg];
  }
}

extern "C" void kernel_launch(void* const* d_in, const int* in_sizes, int n_in,
                              void* d_out, int out_size, void* d_ws, size_t ws_size,
                              hipStream_t stream) {
  const unsigned short* hidden = (const unsigned short*)d_in[0];
  const unsigned short* mask   = (const unsigned short*)d_in[1];
  const unsigned short* gum    = (const unsigned short*)d_in[2];
  const unsigned short* Wq     = (const unsigned short*)d_in[3];
  const unsigned short* bq     = (const unsigned short*)d_in[4];
  const unsigned short* Wk     = (const unsigned short*)d_in[5];
  const unsigned short* bk     = (const unsigned short*)d_in[6];
  const unsigned short* Wv     = (const unsigned short*)d_in[7];
  const unsigned short* bv     = (const unsigned short*)d_in[8];
  const unsigned short* de     = (const unsigned short*)d_in[9];

  int* flag = (int*)d_ws;                                        // 256 B
  _Float16* cvt16 = (_Float16*)((char*)d_ws + 256);              // 10 MB (dead after qkv)
  _Float16* q_ws  = cvt16 + (size_t)5 * 1024 * 1024;             // 4 MB
  _Float16* k_ws  = q_ws + (size_t)2 * 1024 * 1024;              // 4 MB
  _Float16* v_ws  = k_ws + (size_t)2 * 1024 * 1024;              // 4 MB
  _Float16* vT_ws = cvt16;             // reuse cvt16 space after qkv consumed it
  float* out = (float*)d_out;

  detect_dtype<<<1, 64, 0, stream>>>(gum, flag);
  cvt_inputs<<<dim3(2048, 4), 256, 0, stream>>>(hidden, Wq, Wk, Wv, flag, cvt16);
  qkv_gemm<<<dim3(32, 24), 256, 0, stream>>>(cvt16, bq, bk, bv, flag,
                                             q_ws, k_ws, v_ws);
  transpose_v<<<dim3(16, 32), 256, 0, stream>>>(v_ws, vT_ws);
  attn_kernel<<<2048, 256, 0, stream>>>(q_ws, k_ws, vT_ws, de, gum, mask, flag, out);
}